// Round 2
// baseline (515.204 us; speedup 1.0000x reference)
//
#include <hip/hip_runtime.h>

typedef __attribute__((ext_vector_type(4))) float f32x4;
typedef __attribute__((ext_vector_type(8))) short bf16x8;
typedef __attribute__((ext_vector_type(4))) unsigned short us4;
typedef unsigned short ushort_t;

__device__ __forceinline__ float bf2f(ushort_t u){
  union { unsigned int i; float f; } v; v.i = ((unsigned int)u) << 16; return v.f;
}
__device__ __forceinline__ ushort_t f2bf(float f){
  union { float f; unsigned int i; } v; v.f = f;
  unsigned int r = v.i + 0x7fffu + ((v.i >> 16) & 1u);
  return (ushort_t)(r >> 16);
}
// async global->LDS, 16B per lane; LDS dest = wave-uniform base + lane*16
__device__ __forceinline__ void async16(const ushort_t* g, ushort_t* l){
  __builtin_amdgcn_global_load_lds(
      (const __attribute__((address_space(1))) unsigned int*)g,
      (__attribute__((address_space(3))) unsigned int*)l, 16, 0, 0);
}

// ---------------------------------------------------------------------------
// Dtype detection: if the input tensors are f32 (reference dtype), their raw
// ushorts decode as huge/garbage bf16s ~22% of the time. If they're bf16
// (0.02-scale weights), none exceed 2^17. One block, deterministic.
// ---------------------------------------------------------------------------
__global__ void detect_f32(const ushort_t* __restrict__ probe, int* __restrict__ flag){
  const int lane = threadIdx.x;
  int big = 0;
  for (int i = lane; i < 4096; i += 64) {
    const int ex = (probe[i] >> 7) & 0xFF;
    if (ex >= 0x90) big++;            // |bf16| >= 2^17: impossible for real weights
  }
#pragma unroll
  for (int off = 32; off > 0; off >>= 1) big += __shfl_xor(big, off);
  if (lane == 0) *flag = (big > 16) ? 1 : 0;
}

// out[i] = bf16(in[i]); in is f32 if *flag else bf16 (passthrough copy)
__global__ __launch_bounds__(256) void convert_bf16(
    const void* __restrict__ in, ushort_t* __restrict__ out, int n,
    const int* __restrict__ flag)
{
  const bool isf = (*flag != 0);
  const int i = (blockIdx.x * 256 + threadIdx.x) * 4;
  if (i + 4 > n) {
    if (isf) { const float* f = (const float*)in; for (int j = i; j < n; j++) out[j] = f2bf(f[j]); }
    else     { const ushort_t* u = (const ushort_t*)in; for (int j = i; j < n; j++) out[j] = u[j]; }
    return;
  }
  if (isf) {
    f32x4 v = *(const f32x4*)((const float*)in + i);
    us4 o; o[0] = f2bf(v[0]); o[1] = f2bf(v[1]); o[2] = f2bf(v[2]); o[3] = f2bf(v[3]);
    *(us4*)(out + i) = o;
  } else {
    *(us4*)(out + i) = *(const us4*)((const ushort_t*)in + i);
  }
}

// ---------------------------------------------------------------------------
// C[M,N] = A[M,K] @ B[N,K]^T   (bf16 in, fp32 accum). FINAL: output width
// picked by *flag (f32 vs bf16); else bf16.
// 128x128 tile, BK=64, 4 waves 2x2, each wave 4x4 tiles of 16x16x32 MFMA.
// ---------------------------------------------------------------------------
#define BK 64
template<bool FINAL>
__global__ __launch_bounds__(256) void gemm_bt(
    const ushort_t* __restrict__ A, const ushort_t* __restrict__ B,
    ushort_t* __restrict__ C, float* __restrict__ Cf, const int* __restrict__ flag,
    int M, int N, int K)
{
  __shared__ __align__(16) ushort_t As[128*BK];
  __shared__ __align__(16) ushort_t Bs[128*BK];
  const int tid = threadIdx.x;
  const int lane = tid & 63, wave = tid >> 6;
  const int quad = lane >> 4, l16 = lane & 15;
  const int m0 = blockIdx.y * 128, n0 = blockIdx.x * 128;
  const int wm = (wave >> 1) * 64, wn = (wave & 1) * 64;
  const int srow = lane >> 3, sslot = lane & 7;

  f32x4 acc[4][4];
#pragma unroll
  for (int i = 0; i < 4; i++)
#pragma unroll
    for (int j = 0; j < 4; j++) acc[i][j] = (f32x4){0.f,0.f,0.f,0.f};

  for (int k0 = 0; k0 < K; k0 += BK) {
    __syncthreads();
#pragma unroll
    for (int i = 0; i < 4; i++) {
      const int r0 = wave*32 + i*8;
      const int row = r0 + srow;
      const int g = (sslot ^ (row & 7)) * 8;   // swizzled global chunk
      async16(A + (size_t)(m0 + row)*K + k0 + g, &As[r0*64]);
      async16(B + (size_t)(n0 + row)*K + k0 + g, &Bs[r0*64]);
    }
    __syncthreads();
#pragma unroll
    for (int kc = 0; kc < 2; kc++) {
      bf16x8 af[4], bfr[4];
#pragma unroll
      for (int i = 0; i < 4; i++) {
        const int ra = wm + i*16 + l16;
        af[i] = *(const bf16x8*)&As[ra*64 + (((kc*4 + quad) ^ (ra & 7)))*8];
        const int rb = wn + i*16 + l16;
        bfr[i] = *(const bf16x8*)&Bs[rb*64 + (((kc*4 + quad) ^ (rb & 7)))*8];
      }
#pragma unroll
      for (int i = 0; i < 4; i++)
#pragma unroll
        for (int j = 0; j < 4; j++)
          acc[i][j] = __builtin_amdgcn_mfma_f32_16x16x32_bf16(af[i], bfr[j], acc[i][j], 0, 0, 0);
    }
  }
  // epilogue: C/D layout col=lane&15, row=quad*4+reg
  const bool isf = FINAL && (*flag != 0);
#pragma unroll
  for (int i = 0; i < 4; i++) {
    const int rbase = m0 + wm + i*16 + quad*4;
#pragma unroll
    for (int j = 0; j < 4; j++) {
      const int col = n0 + wn + j*16 + l16;
#pragma unroll
      for (int r = 0; r < 4; r++) {
        if (FINAL && isf) Cf[(size_t)(rbase + r)*N + col] = acc[i][j][r];
        else              C [(size_t)(rbase + r)*N + col] = f2bf(acc[i][j][r]);
      }
    }
  }
}

// ---------------------------------------------------------------------------
// Per-128-dim RMSNorm in place (for K). One wave per vector, 2 elems/lane.
// ---------------------------------------------------------------------------
__global__ __launch_bounds__(256) void rmsnorm_rows(
    ushort_t* __restrict__ buf, const ushort_t* __restrict__ gamma, int nvec)
{
  const int vec = blockIdx.x * 4 + (threadIdx.x >> 6);
  const int lane = threadIdx.x & 63;
  if (vec >= nvec) return;
  const size_t base = (size_t)vec * 128 + lane*2;
  unsigned int p = *(const unsigned int*)&buf[base];
  float a = bf2f((ushort_t)(p & 0xffff));
  float b = bf2f((ushort_t)(p >> 16));
  float ss = a*a + b*b;
#pragma unroll
  for (int off = 32; off > 0; off >>= 1) ss += __shfl_xor(ss, off);
  const float sc = rsqrtf(ss * (1.0f/128.0f) + 1e-6f);
  unsigned int gp = *(const unsigned int*)&gamma[lane*2];
  float g0 = bf2f((ushort_t)(gp & 0xffff));
  float g1 = bf2f((ushort_t)(gp >> 16));
  unsigned int o = (unsigned int)f2bf(a*sc*g0) | ((unsigned int)f2bf(b*sc*g1) << 16);
  *(unsigned int*)&buf[base] = o;
}

// ---------------------------------------------------------------------------
// Flash attention, S^T orientation (lane owns one q-row), tanh softcap,
// causal, GQA. Q-RMSNorm + SCALE folded into the Q fragment load.
// Block: 4 waves x 16 q-rows = 64 q rows per (b,h). K-tile = 64 keys.
// ---------------------------------------------------------------------------
__global__ __launch_bounds__(256) void attn_fused(
    const ushort_t* __restrict__ qbuf, const ushort_t* __restrict__ kbuf,
    const ushort_t* __restrict__ vbuf, const ushort_t* __restrict__ qgamma,
    ushort_t* __restrict__ obuf)
{
  __shared__ __align__(16) ushort_t Ks[64*128];    // [key][dim], swizzled
  __shared__ __align__(16) ushort_t VTs[128*64];   // [dim][key], swizzled
  __shared__ __align__(16) ushort_t Ps[4][16*72];  // per-wave P: [qrow][64+pad8]
  const int tid = threadIdx.x;
  const int lane = tid & 63, wave = tid >> 6;
  const int quad = lane >> 4, l16 = lane & 15;
  const int bx = blockIdx.x, h = blockIdx.y, b = blockIdx.z;
  const int kvh = h >> 2;
  const int q0 = bx * 64;
  const size_t bT = (size_t)b * 2048;
  const int qrow = q0 + wave*16 + l16;   // this lane's q row (global in T)

  // ---- Q load + fused RMSNorm (gamma + 1/sqrt(HD) folded in) ----
  const ushort_t* qptr = qbuf + (bT + qrow)*2048 + h*128;
  float qv[4][8];
  float ss = 0.f;
#pragma unroll
  for (int kc = 0; kc < 4; kc++) {
    bf16x8 v = *(const bf16x8*)&qptr[kc*32 + quad*8];
#pragma unroll
    for (int j = 0; j < 8; j++) { float f = bf2f((ushort_t)v[j]); qv[kc][j] = f; ss += f*f; }
  }
  ss += __shfl_xor(ss, 16);
  ss += __shfl_xor(ss, 32);
  const float qsc = rsqrtf(ss*(1.0f/128.0f) + 1e-6f) * 0.08838834764831845f;
  bf16x8 qf[4];
#pragma unroll
  for (int kc = 0; kc < 4; kc++) {
    bf16x8 g = *(const bf16x8*)&qgamma[kc*32 + quad*8];
    bf16x8 o;
#pragma unroll
    for (int j = 0; j < 8; j++) o[j] = (short)f2bf(qv[kc][j] * qsc * bf2f((ushort_t)g[j]));
    qf[kc] = o;
  }

  f32x4 Ob[8];
#pragma unroll
  for (int i = 0; i < 8; i++) Ob[i] = (f32x4){0.f,0.f,0.f,0.f};
  float m_run = -3.0e38f, l_run = 0.f;

  for (int kb = 0; kb <= bx; kb++) {
    __syncthreads();   // previous tile's LDS reads done
    // stage K tile (async, 4 rows x 16 chunks per instr)
#pragma unroll
    for (int i = 0; i < 4; i++) {
      const int r0 = wave*16 + i*4;
      const int row = r0 + (lane >> 4);
      const int g = ((lane & 15) ^ (row & 15)) * 8;
      async16(kbuf + (bT + kb*64 + row)*512 + kvh*128 + g, &Ks[r0*128]);
    }
    // stage V transposed: thread packs (key,key+1) pairs per dim
#pragma unroll
    for (int i = 0; i < 2; i++) {
      const int tau = tid + 256*i;
      const int key = (tau & 31) * 2;
      const int d8 = tau >> 5;           // dim octet 0..15
      const ushort_t* v0 = vbuf + (bT + kb*64 + key)*512 + kvh*128 + d8*8;
      bf16x8 r0v = *(const bf16x8*)v0;
      bf16x8 r1v = *(const bf16x8*)(v0 + 512);
#pragma unroll
      for (int j = 0; j < 8; j++) {
        const int d = d8*8 + j;
        const int slot = (key >> 3) ^ (d & 7);
        unsigned int pk = (unsigned int)(ushort_t)r0v[j] | ((unsigned int)(ushort_t)r1v[j] << 16);
        *(unsigned int*)&VTs[d*64 + slot*8 + (key & 7)] = pk;
      }
    }
    __syncthreads();

    // ---- S^T = K · Q^T : lane col = qrow, rows = keys (quad*4+reg) ----
    f32x4 st[4];
#pragma unroll
    for (int s = 0; s < 4; s++) {
      f32x4 c = (f32x4){0.f,0.f,0.f,0.f};
#pragma unroll
      for (int kc = 0; kc < 4; kc++) {
        const int row = s*16 + l16;
        const bf16x8 kf = *(const bf16x8*)&Ks[row*128 + (((kc*4 + quad) ^ (row & 15)))*8];
        c = __builtin_amdgcn_mfma_f32_16x16x32_bf16(kf, qf[kc], c, 0, 0, 0);
      }
      st[s] = c;
    }

    // softcap + causal mask + online softmax (per-lane: one q-row)
    const bool diag = (kb == bx);
    float rmax = -3.0e38f;
#pragma unroll
    for (int s = 0; s < 4; s++)
#pragma unroll
      for (int r = 0; r < 4; r++) {
        const float x = st[s][r];                       // q·k, SCALE folded
        const float e = __expf(-fabsf(x) * (2.0f/50.0f));
        float capped = copysignf((1.f - e) * __builtin_amdgcn_rcpf(1.f + e) * 50.0f, x);
        if (diag && (s*16 + quad*4 + r) > (wave*16 + l16)) capped = -3.0e38f;
        st[s][r] = capped;
        rmax = fmaxf(rmax, capped);
      }
    rmax = fmaxf(rmax, __shfl_xor(rmax, 16));
    rmax = fmaxf(rmax, __shfl_xor(rmax, 32));
    const float m_new = fmaxf(m_run, rmax);
    const float alpha = __expf(m_run - m_new);
    m_run = m_new;
    float rsum = 0.f;
#pragma unroll
    for (int s = 0; s < 4; s++) {
      us4 pk;
#pragma unroll
      for (int r = 0; r < 4; r++) {
        const float p = __expf(st[s][r] - m_new);
        rsum += p;
        pk[r] = f2bf(p);
      }
      *(us4*)&Ps[wave][l16*72 + s*16 + quad*4] = pk;   // P[qrow][key]
    }
    rsum += __shfl_xor(rsum, 16);
    rsum += __shfl_xor(rsum, 32);
    l_run = l_run * alpha + rsum;
#pragma unroll
    for (int i = 0; i < 8; i++) Ob[i] *= alpha;

    // ---- O^T += V^T · P^T ----
#pragma unroll
    for (int kc = 0; kc < 2; kc++) {
      const bf16x8 pf = *(const bf16x8*)&Ps[wave][l16*72 + kc*32 + quad*8];
#pragma unroll
      for (int dt = 0; dt < 8; dt++) {
        const int d = dt*16 + l16;
        const bf16x8 vf = *(const bf16x8*)&VTs[d*64 + (((kc*4 + quad) ^ (d & 7)))*8];
        Ob[dt] = __builtin_amdgcn_mfma_f32_16x16x32_bf16(vf, pf, Ob[dt], 0, 0, 0);
      }
    }
  }

  // epilogue: lane holds q-row = qrow, dims dt*16 + quad*4 + r
  const float inv_l = __builtin_amdgcn_rcpf(l_run);
  ushort_t* optr = obuf + (bT + qrow)*2048 + h*128;
#pragma unroll
  for (int dt = 0; dt < 8; dt++) {
    us4 pk;
#pragma unroll
    for (int r = 0; r < 4; r++) pk[r] = f2bf(Ob[dt][r] * inv_l);
    *(us4*)&optr[dt*16 + quad*4] = pk;
  }
}

extern "C" void kernel_launch(void* const* d_in, const int* in_sizes, int n_in,
                              void* d_out, int out_size, void* d_ws, size_t ws_size,
                              hipStream_t stream)
{
  int* flag = (int*)d_ws;
  ushort_t* ws = (ushort_t*)d_ws + 8;   // keep 16B alignment
  // bf16 copies of inputs
  ushort_t* xb  = ws;                    // 8388608  (also reused as obuf)
  ushort_t* wqb = xb  + (size_t)8388608; // 4194304
  ushort_t* wkb = wqb + (size_t)4194304; // 1048576
  ushort_t* wvb = wkb + (size_t)1048576; // 1048576
  ushort_t* wob = wvb + (size_t)1048576; // 4194304
  ushort_t* qgb = wob + (size_t)4194304; // 128
  ushort_t* kgb = qgb + 128;             // 128
  ushort_t* qbuf = kgb + 128;            // 8388608
  ushort_t* kbuf = qbuf + (size_t)8388608; // 2097152
  ushort_t* vbuf = kbuf + (size_t)2097152; // 2097152
  ushort_t* obuf = xb;                   // alias: x dead after QKV gemms

  detect_f32<<<1, 64, 0, stream>>>((const ushort_t*)d_in[1], flag);
  convert_bf16<<<8192, 256, 0, stream>>>(d_in[0], xb,  8388608, flag);
  convert_bf16<<<4096, 256, 0, stream>>>(d_in[1], wqb, 4194304, flag);
  convert_bf16<<<1024, 256, 0, stream>>>(d_in[2], wkb, 1048576, flag);
  convert_bf16<<<1024, 256, 0, stream>>>(d_in[3], wvb, 1048576, flag);
  convert_bf16<<<4096, 256, 0, stream>>>(d_in[4], wob, 4194304, flag);
  convert_bf16<<<1,    256, 0, stream>>>(d_in[5], qgb, 128, flag);
  convert_bf16<<<1,    256, 0, stream>>>(d_in[6], kgb, 128, flag);

  gemm_bt<false><<<dim3(16, 32), 256, 0, stream>>>(xb, wqb, qbuf, nullptr, flag, 4096, 2048, 2048);
  gemm_bt<false><<<dim3(4, 32),  256, 0, stream>>>(xb, wkb, kbuf, nullptr, flag, 4096, 512, 2048);
  gemm_bt<false><<<dim3(4, 32),  256, 0, stream>>>(xb, wvb, vbuf, nullptr, flag, 4096, 512, 2048);
  rmsnorm_rows<<<dim3(4096), 256, 0, stream>>>(kbuf, kgb, 16384);
  attn_fused<<<dim3(32, 16, 2), 256, 0, stream>>>(qbuf, kbuf, vbuf, qgb, obuf);
  gemm_bt<true><<<dim3(16, 32), 256, 0, stream>>>(obuf, wob, (ushort_t*)d_out, (float*)d_out, flag, 4096, 2048, 2048);
}

// Round 3
// 385.625 us; speedup vs baseline: 1.3360x; 1.3360x over previous
//
#include <hip/hip_runtime.h>

typedef __attribute__((ext_vector_type(4))) float f32x4;
typedef __attribute__((ext_vector_type(8))) short bf16x8;
typedef __attribute__((ext_vector_type(4))) unsigned short us4;
typedef unsigned short ushort_t;

__device__ __forceinline__ float bf2f(ushort_t u){
  union { unsigned int i; float f; } v; v.i = ((unsigned int)u) << 16; return v.f;
}
__device__ __forceinline__ ushort_t f2bf(float f){
  union { float f; unsigned int i; } v; v.f = f;
  unsigned int r = v.i + 0x7fffu + ((v.i >> 16) & 1u);
  return (ushort_t)(r >> 16);
}
__device__ __forceinline__ void async16(const ushort_t* g, ushort_t* l){
  __builtin_amdgcn_global_load_lds(
      (const __attribute__((address_space(1))) unsigned int*)g,
      (__attribute__((address_space(3))) unsigned int*)l, 16, 0, 0);
}

// ---------------------------------------------------------------------------
// Dtype detection (f32 vs bf16 inputs) — unchanged from round 2 (passed).
// ---------------------------------------------------------------------------
__global__ void detect_f32(const ushort_t* __restrict__ probe, int* __restrict__ flag){
  const int lane = threadIdx.x;
  int big = 0;
  for (int i = lane; i < 4096; i += 64) {
    const int ex = (probe[i] >> 7) & 0xFF;
    if (ex >= 0x90) big++;
  }
#pragma unroll
  for (int off = 32; off > 0; off >>= 1) big += __shfl_xor(big, off);
  if (lane == 0) *flag = (big > 16) ? 1 : 0;
}

// ---------------------------------------------------------------------------
// One fused convert for all 7 inputs (was 7 launches).
// Segment offsets (elems): x 8388608 | wq 4194304 | wk 1048576 | wv 1048576 |
// wo 4194304 | qg 128 | kg 128.  All multiples of 4.
// ---------------------------------------------------------------------------
__global__ __launch_bounds__(256) void convert_all(
    const void* s0, const void* s1, const void* s2, const void* s3,
    const void* s4, const void* s5, const void* s6,
    ushort_t* d0, ushort_t* d1, ushort_t* d2, ushort_t* d3,
    ushort_t* d4, ushort_t* d5, ushort_t* d6,
    const int* __restrict__ flag)
{
  long i = ((long)blockIdx.x * 256 + threadIdx.x) * 4;
  if (i >= 18874624L) return;
  const void* src; ushort_t* dst; long loc;
  if      (i <  8388608L) { src = s0; dst = d0; loc = i; }
  else if (i < 12582912L) { src = s1; dst = d1; loc = i - 8388608L; }
  else if (i < 13631488L) { src = s2; dst = d2; loc = i - 12582912L; }
  else if (i < 14680064L) { src = s3; dst = d3; loc = i - 13631488L; }
  else if (i < 18874368L) { src = s4; dst = d4; loc = i - 14680064L; }
  else if (i < 18874496L) { src = s5; dst = d5; loc = i - 18874368L; }
  else                    { src = s6; dst = d6; loc = i - 18874496L; }
  if (*flag != 0) {
    f32x4 v = *(const f32x4*)((const float*)src + loc);
    us4 o; o[0] = f2bf(v[0]); o[1] = f2bf(v[1]); o[2] = f2bf(v[2]); o[3] = f2bf(v[3]);
    *(us4*)(dst + loc) = o;
  } else {
    *(us4*)(dst + loc) = *(const us4*)((const ushort_t*)src + loc);
  }
}

// ---------------------------------------------------------------------------
// Fused QKV GEMM: C = x @ W^T for W in {wq, wk, wv} chosen per n-block.
// V region writes V^T layout [b][kvh*128+d][t] so attention can async-stage it.
// 128x128 tile, BK=64, m97 structure.
// ---------------------------------------------------------------------------
#define BK 64
__global__ __launch_bounds__(256) void qkv_gemm(
    const ushort_t* __restrict__ A,
    const ushort_t* __restrict__ Wq, const ushort_t* __restrict__ Wk,
    const ushort_t* __restrict__ Wv,
    ushort_t* __restrict__ Q, ushort_t* __restrict__ Kb, ushort_t* __restrict__ Vt)
{
  __shared__ __align__(16) ushort_t As[128*BK];
  __shared__ __align__(16) ushort_t Bs[128*BK];
  const int tid = threadIdx.x;
  const int lane = tid & 63, wave = tid >> 6;
  const int quad = lane >> 4, l16 = lane & 15;
  const int m0 = blockIdx.y * 128;
  const int n0g = blockIdx.x * 128;
  const ushort_t* B; int n0, mode;
  if      (n0g < 2048) { B = Wq; n0 = n0g;        mode = 0; }
  else if (n0g < 2560) { B = Wk; n0 = n0g - 2048; mode = 1; }
  else                 { B = Wv; n0 = n0g - 2560; mode = 2; }
  const int wm = (wave >> 1) * 64, wn = (wave & 1) * 64;
  const int srow = lane >> 3, sslot = lane & 7;

  f32x4 acc[4][4];
#pragma unroll
  for (int i = 0; i < 4; i++)
#pragma unroll
    for (int j = 0; j < 4; j++) acc[i][j] = (f32x4){0.f,0.f,0.f,0.f};

  for (int k0 = 0; k0 < 2048; k0 += BK) {
    __syncthreads();
#pragma unroll
    for (int i = 0; i < 4; i++) {
      const int r0 = wave*32 + i*8;
      const int row = r0 + srow;
      const int g = (sslot ^ (row & 7)) * 8;
      async16(A + (size_t)(m0 + row)*2048 + k0 + g, &As[r0*64]);
      async16(B + (size_t)(n0 + row)*2048 + k0 + g, &Bs[r0*64]);
    }
    __syncthreads();
#pragma unroll
    for (int kc = 0; kc < 2; kc++) {
      bf16x8 af[4], bfr[4];
#pragma unroll
      for (int i = 0; i < 4; i++) {
        const int ra = wm + i*16 + l16;
        af[i] = *(const bf16x8*)&As[ra*64 + (((kc*4 + quad) ^ (ra & 7)))*8];
        const int rb = wn + i*16 + l16;
        bfr[i] = *(const bf16x8*)&Bs[rb*64 + (((kc*4 + quad) ^ (rb & 7)))*8];
      }
#pragma unroll
      for (int i = 0; i < 4; i++)
#pragma unroll
        for (int j = 0; j < 4; j++)
          acc[i][j] = __builtin_amdgcn_mfma_f32_16x16x32_bf16(af[i], bfr[j], acc[i][j], 0, 0, 0);
    }
  }
#pragma unroll
  for (int i = 0; i < 4; i++) {
    const int rbase = m0 + wm + i*16 + quad*4;
#pragma unroll
    for (int j = 0; j < 4; j++) {
      const int col = n0 + wn + j*16 + l16;
      if (mode == 0) {
#pragma unroll
        for (int r = 0; r < 4; r++) Q[(size_t)(rbase + r)*2048 + col] = f2bf(acc[i][j][r]);
      } else if (mode == 1) {
#pragma unroll
        for (int r = 0; r < 4; r++) Kb[(size_t)(rbase + r)*512 + col] = f2bf(acc[i][j][r]);
      } else {
        // V^T: vt[(b*512 + f)][t], f = col, t = rbase&2047 (+r contiguous)
        us4 pk;
#pragma unroll
        for (int r = 0; r < 4; r++) pk[r] = f2bf(acc[i][j][r]);
        const size_t addr = (size_t)((rbase >> 11)*512 + col)*2048 + (rbase & 2047);
        *(us4*)&Vt[addr] = pk;
      }
    }
  }
}

// ---------------------------------------------------------------------------
// Per-128-dim RMSNorm in place (for K).
// ---------------------------------------------------------------------------
__global__ __launch_bounds__(256) void rmsnorm_rows(
    ushort_t* __restrict__ buf, const ushort_t* __restrict__ gamma, int nvec)
{
  const int vec = blockIdx.x * 4 + (threadIdx.x >> 6);
  const int lane = threadIdx.x & 63;
  if (vec >= nvec) return;
  const size_t base = (size_t)vec * 128 + lane*2;
  unsigned int p = *(const unsigned int*)&buf[base];
  float a = bf2f((ushort_t)(p & 0xffff));
  float b = bf2f((ushort_t)(p >> 16));
  float ss = a*a + b*b;
#pragma unroll
  for (int off = 32; off > 0; off >>= 1) ss += __shfl_xor(ss, off);
  const float sc = rsqrtf(ss * (1.0f/128.0f) + 1e-6f);
  unsigned int gp = *(const unsigned int*)&gamma[lane*2];
  float g0 = bf2f((ushort_t)(gp & 0xffff));
  float g1 = bf2f((ushort_t)(gp >> 16));
  unsigned int o = (unsigned int)f2bf(a*sc*g0) | ((unsigned int)f2bf(b*sc*g1) << 16);
  *(unsigned int*)&buf[base] = o;
}

// ---------------------------------------------------------------------------
// Flash attention, S^T orientation. No-max softmax (scores capped to +-50 so
// exp() is bounded: e^50 ~ 5e21 fits f32). Double-buffered async K/V^T
// staging: prefetch tile kb+1 right after the barrier, compute overlaps DMA.
// ---------------------------------------------------------------------------
__global__ __launch_bounds__(256) void attn_fused(
    const ushort_t* __restrict__ qbuf, const ushort_t* __restrict__ kbuf,
    const ushort_t* __restrict__ vtbuf, const ushort_t* __restrict__ qgamma,
    ushort_t* __restrict__ obuf)
{
  __shared__ __align__(16) ushort_t Ks[2][64*128];   // [key][dim], swizzled
  __shared__ __align__(16) ushort_t VTs[2][128*64];  // [dim][key], swizzled
  __shared__ __align__(16) ushort_t Ps[4][16*72];    // per-wave P [qrow][64+pad]
  const int tid = threadIdx.x;
  const int lane = tid & 63, wave = tid >> 6;
  const int quad = lane >> 4, l16 = lane & 15;
  const int bx = 31 - blockIdx.x;          // longest blocks dispatch first
  const int h = blockIdx.y, b = blockIdx.z;
  const int kvh = h >> 2;
  const size_t bT = (size_t)b * 2048;
  const int qrow = bx*64 + wave*16 + l16;
  const size_t vbase = ((size_t)(b*4 + kvh)) * 128 * 2048;

  // ---- Q load + fused RMSNorm (gamma + 1/sqrt(HD) folded in) ----
  const ushort_t* qptr = qbuf + (bT + qrow)*2048 + h*128;
  float qv[4][8];
  float ss = 0.f;
#pragma unroll
  for (int kc = 0; kc < 4; kc++) {
    bf16x8 v = *(const bf16x8*)&qptr[kc*32 + quad*8];
#pragma unroll
    for (int j = 0; j < 8; j++) { float f = bf2f((ushort_t)v[j]); qv[kc][j] = f; ss += f*f; }
  }
  ss += __shfl_xor(ss, 16);
  ss += __shfl_xor(ss, 32);
  const float qsc = rsqrtf(ss*(1.0f/128.0f) + 1e-6f) * 0.08838834764831845f;
  bf16x8 qf[4];
#pragma unroll
  for (int kc = 0; kc < 4; kc++) {
    bf16x8 g = *(const bf16x8*)&qgamma[kc*32 + quad*8];
    bf16x8 o;
#pragma unroll
    for (int j = 0; j < 8; j++) o[j] = (short)f2bf(qv[kc][j] * qsc * bf2f((ushort_t)g[j]));
    qf[kc] = o;
  }

  f32x4 Ob[8];
#pragma unroll
  for (int i = 0; i < 8; i++) Ob[i] = (f32x4){0.f,0.f,0.f,0.f};
  float l_run = 0.f;

  // staging helpers (wave-cooperative, async16)
  auto stageK = [&](int kb, int bsel){
#pragma unroll
    for (int i = 0; i < 4; i++) {
      const int r0 = wave*16 + i*4;
      const int row = r0 + (lane >> 4);
      const int g = ((lane & 15) ^ (row & 15)) * 8;
      async16(kbuf + (bT + kb*64 + row)*512 + kvh*128 + g, &Ks[bsel][r0*128]);
    }
  };
  auto stageV = [&](int kb, int bsel){
#pragma unroll
    for (int i = 0; i < 4; i++) {
      const int r0 = wave*32 + i*8;
      const int d = r0 + (lane >> 3);
      const int g = ((lane & 7) ^ (d & 7)) * 8;
      async16(vtbuf + vbase + (size_t)d*2048 + kb*64 + g, &VTs[bsel][r0*64]);
    }
  };

  stageK(0, 0); stageV(0, 0);

  for (int kb = 0; kb <= bx; kb++) {
    __syncthreads();                 // drains stage(kb); prev compute done
    if (kb < bx) { stageK(kb+1, (kb+1)&1); stageV(kb+1, (kb+1)&1); }
    const int cur = kb & 1;

    // ---- S^T = K · Q^T ----
    f32x4 st[4];
#pragma unroll
    for (int s = 0; s < 4; s++) {
      f32x4 c = (f32x4){0.f,0.f,0.f,0.f};
#pragma unroll
      for (int kc = 0; kc < 4; kc++) {
        const int row = s*16 + l16;
        const bf16x8 kf = *(const bf16x8*)&Ks[cur][row*128 + (((kc*4 + quad) ^ (row & 15)))*8];
        c = __builtin_amdgcn_mfma_f32_16x16x32_bf16(kf, qf[kc], c, 0, 0, 0);
      }
      st[s] = c;
    }

    // softcap + causal + no-max softmax: p = exp(50*tanh(x/50)), masked -> 0
    const bool diag = (kb == bx);
    const int myq = wave*16 + l16;   // unused rows masked against this
    float rsum = 0.f;
#pragma unroll
    for (int s = 0; s < 4; s++) {
      us4 pk;
#pragma unroll
      for (int r = 0; r < 4; r++) {
        const float x = st[s][r];
        const float e = __expf(x * -0.04f);               // e^{-2x/50}
        const float t = (1.f - e) * __builtin_amdgcn_rcpf(1.f + e);
        float p = __expf(t * 50.f);
        if (diag && (s*16 + quad*4 + r) > myq) p = 0.f;
        rsum += p;
        pk[r] = f2bf(p);
      }
      *(us4*)&Ps[wave][l16*72 + s*16 + quad*4] = pk;
    }
    l_run += rsum;                   // quad-reduction deferred to epilogue

    // ---- O^T += V^T · P^T ----
#pragma unroll
    for (int kc = 0; kc < 2; kc++) {
      const bf16x8 pf = *(const bf16x8*)&Ps[wave][l16*72 + kc*32 + quad*8];
#pragma unroll
      for (int dt = 0; dt < 8; dt++) {
        const int d = dt*16 + l16;
        const bf16x8 vf = *(const bf16x8*)&VTs[cur][d*64 + (((kc*4 + quad) ^ (d & 7)))*8];
        Ob[dt] = __builtin_amdgcn_mfma_f32_16x16x32_bf16(vf, pf, Ob[dt], 0, 0, 0);
      }
    }
  }

  l_run += __shfl_xor(l_run, 16);
  l_run += __shfl_xor(l_run, 32);
  const float inv_l = __builtin_amdgcn_rcpf(l_run);
  ushort_t* optr = obuf + (bT + qrow)*2048 + h*128;
#pragma unroll
  for (int dt = 0; dt < 8; dt++) {
    us4 pk;
#pragma unroll
    for (int r = 0; r < 4; r++) pk[r] = f2bf(Ob[dt][r] * inv_l);
    *(us4*)&optr[dt*16 + quad*4] = pk;
  }
}

// ---------------------------------------------------------------------------
// Final GEMM C = A @ B^T with f32-or-bf16 output per flag.
// ---------------------------------------------------------------------------
__global__ __launch_bounds__(256) void gemm_final(
    const ushort_t* __restrict__ A, const ushort_t* __restrict__ B,
    ushort_t* __restrict__ C, float* __restrict__ Cf, const int* __restrict__ flag)
{
  __shared__ __align__(16) ushort_t As[128*BK];
  __shared__ __align__(16) ushort_t Bs[128*BK];
  const int tid = threadIdx.x;
  const int lane = tid & 63, wave = tid >> 6;
  const int quad = lane >> 4, l16 = lane & 15;
  const int m0 = blockIdx.y * 128, n0 = blockIdx.x * 128;
  const int wm = (wave >> 1) * 64, wn = (wave & 1) * 64;
  const int srow = lane >> 3, sslot = lane & 7;

  f32x4 acc[4][4];
#pragma unroll
  for (int i = 0; i < 4; i++)
#pragma unroll
    for (int j = 0; j < 4; j++) acc[i][j] = (f32x4){0.f,0.f,0.f,0.f};

  for (int k0 = 0; k0 < 2048; k0 += BK) {
    __syncthreads();
#pragma unroll
    for (int i = 0; i < 4; i++) {
      const int r0 = wave*32 + i*8;
      const int row = r0 + srow;
      const int g = (sslot ^ (row & 7)) * 8;
      async16(A + (size_t)(m0 + row)*2048 + k0 + g, &As[r0*64]);
      async16(B + (size_t)(n0 + row)*2048 + k0 + g, &Bs[r0*64]);
    }
    __syncthreads();
#pragma unroll
    for (int kc = 0; kc < 2; kc++) {
      bf16x8 af[4], bfr[4];
#pragma unroll
      for (int i = 0; i < 4; i++) {
        const int ra = wm + i*16 + l16;
        af[i] = *(const bf16x8*)&As[ra*64 + (((kc*4 + quad) ^ (ra & 7)))*8];
        const int rb = wn + i*16 + l16;
        bfr[i] = *(const bf16x8*)&Bs[rb*64 + (((kc*4 + quad) ^ (rb & 7)))*8];
      }
#pragma unroll
      for (int i = 0; i < 4; i++)
#pragma unroll
        for (int j = 0; j < 4; j++)
          acc[i][j] = __builtin_amdgcn_mfma_f32_16x16x32_bf16(af[i], bfr[j], acc[i][j], 0, 0, 0);
    }
  }
  const bool isf = (*flag != 0);
#pragma unroll
  for (int i = 0; i < 4; i++) {
    const int rbase = m0 + wm + i*16 + quad*4;
#pragma unroll
    for (int j = 0; j < 4; j++) {
      const int col = n0 + wn + j*16 + l16;
#pragma unroll
      for (int r = 0; r < 4; r++) {
        if (isf) Cf[(size_t)(rbase + r)*2048 + col] = acc[i][j][r];
        else     C [(size_t)(rbase + r)*2048 + col] = f2bf(acc[i][j][r]);
      }
    }
  }
}

extern "C" void kernel_launch(void* const* d_in, const int* in_sizes, int n_in,
                              void* d_out, int out_size, void* d_ws, size_t ws_size,
                              hipStream_t stream)
{
  int* flag = (int*)d_ws;
  ushort_t* ws = (ushort_t*)d_ws + 8;
  ushort_t* xb  = ws;                        // 8388608 (aliased as obuf later)
  ushort_t* wqb = xb  + (size_t)8388608;     // 4194304
  ushort_t* wkb = wqb + (size_t)4194304;     // 1048576
  ushort_t* wvb = wkb + (size_t)1048576;     // 1048576
  ushort_t* wob = wvb + (size_t)1048576;     // 4194304
  ushort_t* qgb = wob + (size_t)4194304;     // 128
  ushort_t* kgb = qgb + 128;                 // 128
  ushort_t* qbuf = kgb + 128;                // 8388608
  ushort_t* kbuf  = qbuf + (size_t)8388608;  // 2097152
  ushort_t* vtbuf = kbuf + (size_t)2097152;  // 2097152
  ushort_t* obuf = xb;                       // x dead after qkv_gemm

  detect_f32<<<1, 64, 0, stream>>>((const ushort_t*)d_in[1], flag);
  convert_all<<<18433, 256, 0, stream>>>(
      d_in[0], d_in[1], d_in[2], d_in[3], d_in[4], d_in[5], d_in[6],
      xb, wqb, wkb, wvb, wob, qgb, kgb, flag);

  qkv_gemm<<<dim3(24, 32), 256, 0, stream>>>(xb, wqb, wkb, wvb, qbuf, kbuf, vtbuf);
  rmsnorm_rows<<<dim3(4096), 256, 0, stream>>>(kbuf, kgb, 16384);
  attn_fused<<<dim3(32, 16, 2), 256, 0, stream>>>(qbuf, kbuf, vtbuf, qgb, obuf);
  gemm_final<<<dim3(16, 32), 256, 0, stream>>>(obuf, wob, (ushort_t*)d_out, (float*)d_out, flag);
}